// Round 6
// baseline (258.593 us; speedup 1.0000x reference)
//
#include <hip/hip_runtime.h>
#include <hip/hip_fp16.h>

#define NEGV  (-1e30f)
#define LOG2E 1.44269504088896340736f
#define LN2F  0.69314718055994530942f

// Fixed problem sizes from the reference setup_inputs()
constexpr int Tn = 1024;          // time steps
constexpr int Bn = 128;           // batch
constexpr int Cn = 96;            // classes
constexpr int Sn = 200;           // max target length
constexpr int Ln = 2 * Sn + 1;    // extended target length = 401
constexpr int W  = 7;             // states per lane (64*7 = 448 >= 401)

__device__ __forceinline__ float fexp2(float x) {
#if __has_builtin(__builtin_amdgcn_exp2f)
    return __builtin_amdgcn_exp2f(x);
#else
    return exp2f(x);
#endif
}
__device__ __forceinline__ float flog2(float x) {
#if __has_builtin(__builtin_amdgcn_logf)
    return __builtin_amdgcn_logf(x);
#else
    return __log2f(x);
#endif
}

// shfl_up by 1 across the full wave via DPP WF_SR1 (0x138): dest[i] = src[i-1].
// Lane 0 receives `old` = 0 (consumer-side zl/g1z/g0z masking zeroes it anyway).
__device__ __forceinline__ float shup1(float x) {
    return __int_as_float(__builtin_amdgcn_update_dpp(
        0, __float_as_int(x), 0x138, 0xf, 0xf, false));
}

// Wave-wide max via DPP; result valid in lane 63.
__device__ __forceinline__ float wave_max_dpp_to_lane63(float x) {
    #define DPP_MAX(ctrl)                                                   \
        x = fmaxf(x, __int_as_float(__builtin_amdgcn_update_dpp(            \
                __float_as_int(x), __float_as_int(x), (ctrl), 0xf, 0xf, false)))
    DPP_MAX(0x111);  // row_shr:1
    DPP_MAX(0x112);  // row_shr:2
    DPP_MAX(0x114);  // row_shr:4
    DPP_MAX(0x118);  // row_shr:8
    DPP_MAX(0x142);  // row_bcast15
    DPP_MAX(0x143);  // row_bcast31 -> lane63 = max(all)
    #undef DPP_MAX
    return x;
}

// ---------------------------------------------------------------------------
// Self-feeding serial kernel: ONE wave per batch. No producers, no LDS data
// path, no barriers, no fp16 round-trip. Each lane global-loads the 7 f32
// log-probs its own 7 states need (per-lane class indices are constant over
// t), 8 rows ahead in a static register ring (56 outstanding loads).
// Emit probs computed in-wave: e = exp2(fma(lp, LOG2E, la)), la = -12800 for
// dead states (exp2 -> 0), 0 for live. Recurrence/rescale/capture identical
// to the proven passing kernel.
// ---------------------------------------------------------------------------
__global__ __launch_bounds__(64, 1) void ctc_self_kernel(
    const float* __restrict__ lp,   // [T, B, C]
    const int*   __restrict__ tg,   // [B, S]
    const int*   __restrict__ il,
    const int*   __restrict__ tl,
    float*       __restrict__ out_pb)
{
    const int b    = blockIdx.x;
    const int lane = threadIdx.x;
    __shared__ float endv[2];

    const int inlen = il[b];
    const int tlen  = tl[b];
    const int ee0 = 2 * tlen - 1;
    const int ee1 = 2 * tlen;

    // Skip-transition gate per state (1.0 allowed, 0.0 forbidden).
    auto mk_gate = [&](int j) -> float {
        const int s = lane * W + j;
        if (s < Ln && (s & 1) && s >= 3) {
            const int k = s >> 1;
            if (tg[b * Sn + k] != tg[b * Sn + k - 1]) return 1.0f;
        }
        return 0.0f;
    };
    const float g0 = mk_gate(0), g1 = mk_gate(1), g2 = mk_gate(2),
                g3 = mk_gate(3), g4 = mk_gate(4), g5 = mk_gate(5),
                g6 = mk_gate(6);

    const float zl  = (lane == 0) ? 0.0f : 1.0f;
    const float g1z = g1 * zl;
    const float g0z = g0 * zl;

    // Per-lane gather class indices (constant over t) + dead-state addend.
    int   cidx[W];
    float la0, la1, la2, la3, la4, la5, la6;
    {
        float la[W];
        #pragma unroll
        for (int j = 0; j < W; ++j) {
            const int s = lane * W + j;
            cidx[j] = (s < Ln && (s & 1)) ? tg[b * Sn + (s >> 1)] : 0;
            la[j]   = (s < Ln) ? 0.0f : -12800.0f;   // exp2(x+la) = 0 for dead
        }
        la0 = la[0]; la1 = la[1]; la2 = la[2]; la3 = la[3];
        la4 = la[4]; la5 = la[5]; la6 = la[6];
    }

    // alpha(t=0): only states 0,1 live (both on lane 0). Linear domain.
    float a0v, a1v, a2v, a3v, a4v, a5v, a6v;
    {
        const float* rp0 = lp + (size_t)b * Cn;        // t = 0
        const float x0 = rp0[cidx[0]];
        const float x1 = rp0[cidx[1]];
        a0v = (lane == 0) ? fexp2(x0 * LOG2E) : 0.0f;
        a1v = (lane == 0) ? fexp2(x1 * LOG2E) : 0.0f;
        a2v = 0.0f; a3v = 0.0f; a4v = 0.0f; a5v = 0.0f; a6v = 0.0f;
    }
    float pm1 = 0.0f, pm2 = 0.0f;   // pipelined boundary values (0 at t=0)

    // 8-row register ring of raw log-probs; rows 1..8 preloaded.
    float rQ[8][W];
    #pragma unroll
    for (int r = 1; r <= 8; ++r) {
        const float* rp_ = lp + ((size_t)r * Bn + b) * Cn;
        #pragma unroll
        for (int j = 0; j < W; ++j) rQ[r & 7][j] = rp_[cidx[j]];
    }

    int K = 0;          // alpha_true = alpha_stored * 2^{-K} (wave-uniform)
    int k_cap = 0;
    int t = 1;

#define CAP(J, AJ) { const int s_ = lane * W + (J);                         \
                     if (s_ == ee0) endv[0] = (AJ);                         \
                     if (s_ == ee1) endv[1] = (AJ); }

// One step: consume ring slot SLOT (row t), then refill it with row t+8.
#define CTC_STEP(SLOT)                                                      \
  {                                                                         \
    const int tt = (t + 8 < Tn) ? (t + 8) : (Tn - 1);                       \
    const float e0m = fexp2(fmaf(rQ[SLOT][0], LOG2E, la0));                 \
    const float e1m = fexp2(fmaf(rQ[SLOT][1], LOG2E, la1));                 \
    const float e2m = fexp2(fmaf(rQ[SLOT][2], LOG2E, la2));                 \
    const float e3m = fexp2(fmaf(rQ[SLOT][3], LOG2E, la3));                 \
    const float e4m = fexp2(fmaf(rQ[SLOT][4], LOG2E, la4));                 \
    const float e5m = fexp2(fmaf(rQ[SLOT][5], LOG2E, la5));                 \
    const float e6m = fexp2(fmaf(rQ[SLOT][6], LOG2E, la6));                 \
    { const float* rp_ = lp + ((size_t)tt * Bn + b) * Cn;                   \
      _Pragma("unroll")                                                     \
      for (int j = 0; j < W; ++j) rQ[SLOT][j] = rp_[cidx[j]]; }             \
    const float n6 = fmaf(g6, a4v, a6v + a5v) * e6m;                        \
    const float n5 = fmaf(g5, a3v, a5v + a4v) * e5m;                        \
    const float npm1 = shup1(n6);   /* consumed NEXT step only */           \
    const float npm2 = shup1(n5);                                           \
    const float n4 = fmaf(g4, a2v, a4v + a3v) * e4m;                        \
    const float n3 = fmaf(g3, a1v, a3v + a2v) * e3m;                        \
    const float n2 = fmaf(g2, a0v, a2v + a1v) * e2m;                        \
    const float n1 = fmaf(g1z, pm1, a1v + a0v) * e1m;                       \
    const float n0 = fmaf(g0z, pm2, fmaf(zl, pm1, a0v)) * e0m;              \
    a6v = n6; a5v = n5; a4v = n4; a3v = n3; a2v = n2; a1v = n1; a0v = n0;   \
    pm1 = npm1; pm2 = npm2;                                                 \
    if (t == inlen - 1) {                                                   \
      CAP(0, a0v); CAP(1, a1v); CAP(2, a2v); CAP(3, a3v);                   \
      CAP(4, a4v); CAP(5, a5v); CAP(6, a6v);                                \
      k_cap = K;                                                            \
    }                                                                       \
    ++t;                                                                    \
  }

#define BMAX(J, AJ) { const int s_ = lane * W + (J);                        \
                      if (s_ >= ell && s_ <= ee1) mx = fmaxf(mx, (AJ)); }

    #pragma unroll 1
    for (int c = 0; c < Tn / 8; ++c) {      // 128 chunks -> t = 1..1024
        CTC_STEP(1); CTC_STEP(2); CTC_STEP(3); CTC_STEP(4);
        CTC_STEP(5); CTC_STEP(6); CTC_STEP(7); CTC_STEP(0);

        // ---- band-anchored rescale (exact powers of 2), once per 8 steps ----
        const int ell = (2 * tlen - 1) - 2 * (inlen - t);
        float mx = 0.0f;
        BMAX(0, a0v); BMAX(1, a1v); BMAX(2, a2v); BMAX(3, a3v);
        BMAX(4, a4v); BMAX(5, a5v); BMAX(6, a6v);
        const float mxr = wave_max_dpp_to_lane63(mx);
        const int  smx = __builtin_amdgcn_readlane(__float_as_int(mxr), 63);
        const int  eb  = (smx >> 23) & 0xff;
        const bool nz  = (smx > 0) && (eb < 255);
        const float scale = nz ? __int_as_float((254 - eb) << 23) : 1.0f;
        K += nz ? (127 - eb) : 0;
        a0v *= scale; a1v *= scale; a2v *= scale; a3v *= scale;
        a4v *= scale; a5v *= scale; a6v *= scale;
        pm1 *= scale; pm2 *= scale;
    }

#undef BMAX
#undef CTC_STEP
#undef CAP

    __syncthreads();
    if (lane == 0) {
        const float sum = endv[0] + endv[1];
        const float ll2 = flog2(sum) - (float)k_cap;     // log2 of true prob
        float lb = -(ll2 * LN2F);                        // natural-log loss
        if (lb > 1e29f || !(lb == lb)) lb = 0.0f;        // zero_infinity
        out_pb[b] = lb / (float)tlen;                    // mean pre-division
    }
}

// ---------------------------------------------------------------------------
// Fallback (proven R1 kernel), used only if ws cannot hold even pb.
// ---------------------------------------------------------------------------
__global__ __launch_bounds__(448) void ctc_fallback_kernel(
    const float* __restrict__ lp, const int* __restrict__ tg,
    const int* __restrict__ il, const int* __restrict__ tl,
    float* __restrict__ out_pb)
{
    const int b   = blockIdx.x;
    const int tid = threadIdx.x;

    __shared__ float alpha[2][Ln];
    __shared__ float lprow[2][Cn];
    __shared__ float endv[2];

    const int inlen = il[b];
    const int tlen  = tl[b];
    const int e0 = 2 * tlen - 1;
    const int e1 = 2 * tlen;

    const bool active = (tid < Ln);
    int  myclass = 0;
    bool allow   = false;
    if (active && (tid & 1)) {
        const int k = tid >> 1;
        myclass = tg[b * Sn + k];
        if (tid >= 3) allow = (myclass != tg[b * Sn + k - 1]);
    }

    const float* lpb = lp + (size_t)b * Cn;
    if (tid < Cn) lprow[0][tid] = lpb[tid];

    float vv[4] = {0.f, 0.f, 0.f, 0.f};
    if (tid < Cn) {
        vv[1] = lpb[(size_t)1 * Bn * Cn + tid];
        vv[2] = lpb[(size_t)2 * Bn * Cn + tid];
        vv[3] = lpb[(size_t)3 * Bn * Cn + tid];
        vv[0] = lpb[(size_t)4 * Bn * Cn + tid];
    }
    __syncthreads();
    if (active) alpha[0][tid] = (tid < 2) ? lprow[0][myclass] : NEGV;

    int cur = 0;
    #pragma unroll 4
    for (int t = 1; t < Tn; ++t) {
        if (tid < Cn) {
            lprow[t & 1][tid] = vv[t & 3];
            if (t + 4 < Tn)
                vv[t & 3] = lpb[(size_t)(t + 4) * Bn * Cn + tid];
        }
        __syncthreads();
        if (active) {
            const float a0 = alpha[cur][tid];
            const float a1 = (tid >= 1) ? alpha[cur][tid - 1] : NEGV;
            const float a2 = allow ? alpha[cur][tid - 2] : NEGV;
            const float m  = fmaxf(a0, fmaxf(a1, a2));
            const float nv = m + __logf(__expf(a0 - m) + __expf(a1 - m) + __expf(a2 - m))
                           + lprow[t & 1][myclass];
            alpha[cur ^ 1][tid] = nv;
            if (t == inlen - 1) {
                if (tid == e0) endv[0] = nv;
                if (tid == e1) endv[1] = nv;
            }
        }
        cur ^= 1;
    }
    __syncthreads();

    if (tid == 0) {
        const float x = endv[0], y = endv[1];
        const float m = fmaxf(x, y);
        const float ll = m + __logf(__expf(x - m) + __expf(y - m));
        float lb = -ll;
        if (lb > 1e29f) lb = 0.f;
        out_pb[b] = lb / (float)tlen;
    }
}

// Mean of 128 per-batch losses -> scalar.
__global__ void reduce_mean_kernel(const float* __restrict__ pb,
                                   float* __restrict__ out)
{
    const int l = threadIdx.x;
    float s = pb[l] + pb[l + 64];
    #pragma unroll
    for (int o = 32; o; o >>= 1) s += __shfl_down(s, o);
    if (l == 0) out[0] = s * (1.0f / (float)Bn);
}

extern "C" void kernel_launch(void* const* d_in, const int* in_sizes, int n_in,
                              void* d_out, int out_size, void* d_ws, size_t ws_size,
                              hipStream_t stream)
{
    const float* lp = (const float*)d_in[0];
    const int*   tg = (const int*)d_in[1];
    const int*   il = (const int*)d_in[2];
    const int*   tl = (const int*)d_in[3];
    float* out = (float*)d_out;

    if (ws_size >= 4096) {
        float* pb = (float*)d_ws;
        ctc_self_kernel<<<Bn, 64, 0, stream>>>(lp, tg, il, tl, pb);
        reduce_mean_kernel<<<1, 64, 0, stream>>>(pb, out);
    } else {
        float* pb = (float*)d_ws;
        ctc_fallback_kernel<<<Bn, 448, 0, stream>>>(lp, tg, il, tl, pb);
        reduce_mean_kernel<<<1, 64, 0, stream>>>(pb, out);
    }
}